// Round 8
// baseline (890.171 us; speedup 1.0000x reference)
//
#include <hip/hip_runtime.h>
#include <hip/hip_bf16.h>
#include <cstdint>
#include <cstddef>

#define N_NODES 100000
#define N_EDGES 1600000
#define F_IN 512
#define H1F 64
#define H2F 32
#define NCF 16
#define NB 782            // buckets of 128 nodes: (100000+127)/128

typedef __attribute__((ext_vector_type(8))) short bf16x8;
typedef __attribute__((ext_vector_type(4))) float f32x4;

__device__ inline short f2bf(float f) {
    // RNE f32 -> bf16 (inputs are finite, no NaN handling needed)
    uint32_t u = __builtin_bit_cast(uint32_t, f);
    return (short)((u + 0x7FFF + ((u >> 16) & 1)) >> 16);
}

// ---------------------------------------------------------------------------
// B1: bucket histogram over dst>>7, LDS pre-aggregated (782 counters)
// ---------------------------------------------------------------------------
__global__ __launch_bounds__(256) void bhist_kernel(const int* __restrict__ dst,
                                                    int* __restrict__ bcnt) {
    __shared__ int lh[NB];
    for (int i = threadIdx.x; i < NB; i += 256) lh[i] = 0;
    __syncthreads();
    for (int e = blockIdx.x * 256 + threadIdx.x; e < N_EDGES; e += 256 * 256)
        atomicAdd(&lh[dst[e] >> 7], 1);
    __syncthreads();
    for (int i = threadIdx.x; i < NB; i += 256) {
        int v = lh[i];
        if (v) atomicAdd(&bcnt[i], v);
    }
}

// ---------------------------------------------------------------------------
// B2: exclusive scan of bcnt[NB] -> boff[NB+1], init bcur; row_ptr[N]=E
// ---------------------------------------------------------------------------
__global__ __launch_bounds__(1024) void bscan_kernel(const int* __restrict__ bcnt,
                                                     int* __restrict__ boff,
                                                     int* __restrict__ bcur,
                                                     int* __restrict__ row_ptr) {
    __shared__ int s[1024];
    int t = threadIdx.x;
    int v = (t < NB) ? bcnt[t] : 0;
    s[t] = v;
    __syncthreads();
    for (int o = 1; o < 1024; o <<= 1) {
        int a = (t >= o) ? s[t - o] : 0;
        __syncthreads();
        s[t] += a;
        __syncthreads();
    }
    if (t < NB) {
        int ex = s[t] - v;
        boff[t] = ex;
        bcur[t] = ex;
    }
    if (t == 0) {
        boff[NB] = N_EDGES;
        row_ptr[N_NODES] = N_EDGES;
    }
}

// ---------------------------------------------------------------------------
// B3: scatter packed (src | local_dst<<17) into bucket-ordered ebuf.
// Active write front = 782 lines (~50 KB) -> lines fill before eviction.
// ---------------------------------------------------------------------------
__global__ __launch_bounds__(256) void bscatter_kernel(const int* __restrict__ src,
                                                       const int* __restrict__ dst,
                                                       int* __restrict__ bcur,
                                                       int* __restrict__ ebuf) {
    int e = blockIdx.x * 256 + threadIdx.x;
    if (e < N_EDGES) {
        int d = dst[e];
        int b = d >> 7;
        int pos = atomicAdd(&bcur[b], 1);
        ebuf[pos] = src[e] | ((d & 127) << 17);
    }
}

// ---------------------------------------------------------------------------
// B4: per-bucket fine CSR build entirely in LDS; col writes confined to the
// bucket's contiguous ~8 KB segment (L2-resident). Also row_ptr + dinv.
// ---------------------------------------------------------------------------
__global__ __launch_bounds__(256) void bbuild_kernel(const int* __restrict__ ebuf,
                                                     const int* __restrict__ boff,
                                                     int* __restrict__ row_ptr,
                                                     int* __restrict__ col,
                                                     float* __restrict__ dinv) {
    __shared__ int lcnt[128], lexc[128];
    int b = blockIdx.x;
    int beg = boff[b], end = boff[b + 1];
    int t = threadIdx.x;
    if (t < 128) lcnt[t] = 0;
    __syncthreads();
    for (int j = beg + t; j < end; j += 256)
        atomicAdd(&lcnt[(ebuf[j] >> 17) & 127], 1);
    __syncthreads();
    if (t < 128) lexc[t] = lcnt[t];
    __syncthreads();
    for (int o = 1; o < 128; o <<= 1) {
        int a = (t < 128 && t >= o) ? lexc[t - o] : 0;
        __syncthreads();
        if (t < 128) lexc[t] += a;
        __syncthreads();
    }
    int node0 = b << 7;
    if (t < 128) {
        int n = node0 + t;
        if (n < N_NODES) {
            int ex = lexc[t] - lcnt[t];        // exclusive
            row_ptr[n] = beg + ex;
            dinv[n] = rsqrtf((float)(lcnt[t] + 1));
            lexc[t] = ex;                      // reuse as cursor
        }
    }
    __syncthreads();
    for (int j = beg + t; j < end; j += 256) {
        int v = ebuf[j];
        int li = (v >> 17) & 127;
        int p = atomicAdd(&lexc[li], 1);
        col[beg + p] = v & 0x1FFFF;
    }
}

// ---------------------------------------------------------------------------
// GEMM1 (bf16 MFMA): out[r][c] = dinv[r] * sum_k x[r][k]*W[k][c]
// M=100000, K=512, N=64. BM=128, BK=32, 256 threads = 4 waves,
// wave-tile 32 rows x 64 cols, mfma_f32_16x16x32_bf16, f32 accum.
// ---------------------------------------------------------------------------
__global__ __launch_bounds__(256) void gemm1_mfma(const float* __restrict__ x,
                                                  const float* __restrict__ W,
                                                  const float* __restrict__ dinv,
                                                  float* __restrict__ out) {
    __shared__ short As[2][4096];   // [kg]*1024 + (r ^ (kg<<2))*8 + i
    __shared__ short Bs[2][2048];   // byte: c*64 + ((kglocal*16) ^ ((c&3)<<4))
    const int tid = threadIdx.x;
    const int L = tid & 63;
    const int w = tid >> 6;          // wave 0..3
    const int brow = blockIdx.x * 128;

    f32x4 acc[2][4] = {};

    auto stageA = [&](int kt, int buf) {
        #pragma unroll
        for (int h = 0; h < 2; ++h) {
            int r  = (tid >> 2) + h * 64;   // 0..127
            int kg = tid & 3;               // k-group of 8
            int gr = brow + r;
            float4 v0 = make_float4(0.f, 0.f, 0.f, 0.f);
            float4 v1 = make_float4(0.f, 0.f, 0.f, 0.f);
            if (gr < N_NODES) {
                const float* p = &x[(size_t)gr * F_IN + kt * 32 + kg * 8];
                v0 = *reinterpret_cast<const float4*>(p);
                v1 = *reinterpret_cast<const float4*>(p + 4);
            }
            short t8[8] = {f2bf(v0.x), f2bf(v0.y), f2bf(v0.z), f2bf(v0.w),
                           f2bf(v1.x), f2bf(v1.y), f2bf(v1.z), f2bf(v1.w)};
            *reinterpret_cast<bf16x8*>(&As[buf][kg * 1024 + (r ^ (kg << 2)) * 8]) =
                *reinterpret_cast<bf16x8*>(t8);
        }
    };
    auto stageB = [&](int kt, int buf) {
        int k0 = kt * 32 + w * 8;
        short t8[8];
        #pragma unroll
        for (int i = 0; i < 8; ++i) t8[i] = f2bf(W[(size_t)(k0 + i) * H1F + L]);
        int byteoff = L * 64 + ((w * 16) ^ ((L & 3) << 4));
        *reinterpret_cast<bf16x8*>((char*)Bs[buf] + byteoff) =
            *reinterpret_cast<bf16x8*>(t8);
    };
    auto compute = [&](int buf) {
        const int kg = L >> 4;            // 0..3  (k = kg*8 + i)
        const int lr = L & 15;
        int r0 = w * 32 + lr;
        int r1 = r0 + 16;
        bf16x8 a0 = *reinterpret_cast<bf16x8*>(&As[buf][kg * 1024 + (r0 ^ (kg << 2)) * 8]);
        bf16x8 a1 = *reinterpret_cast<bf16x8*>(&As[buf][kg * 1024 + (r1 ^ (kg << 2)) * 8]);
        #pragma unroll
        for (int ni = 0; ni < 4; ++ni) {
            int c = ni * 16 + lr;
            bf16x8 b = *reinterpret_cast<bf16x8*>(
                (char*)Bs[buf] + c * 64 + ((kg * 16) ^ ((c & 3) << 4)));
            acc[0][ni] = __builtin_amdgcn_mfma_f32_16x16x32_bf16(a0, b, acc[0][ni], 0, 0, 0);
            acc[1][ni] = __builtin_amdgcn_mfma_f32_16x16x32_bf16(a1, b, acc[1][ni], 0, 0, 0);
        }
    };

    stageA(0, 0);
    stageB(0, 0);
    __syncthreads();
    for (int kt = 0; kt < 16; ++kt) {
        int cur = kt & 1;
        if (kt < 15) {
            stageA(kt + 1, cur ^ 1);
            stageB(kt + 1, cur ^ 1);
        }
        compute(cur);
        __syncthreads();
    }

    // epilogue: D mapping col=lane&15, row=(lane>>4)*4+i  [m89-verified]
    #pragma unroll
    for (int mi = 0; mi < 2; ++mi) {
        #pragma unroll
        for (int i = 0; i < 4; ++i) {
            int row = brow + w * 32 + mi * 16 + (L >> 4) * 4 + i;
            if (row < N_NODES) {
                float dv = dinv[row];
                #pragma unroll
                for (int ni = 0; ni < 4; ++ni)
                    out[(size_t)row * H1F + ni * 16 + (L & 15)] = acc[mi][ni][i] * dv;
            }
        }
    }
}

// ---------------------------------------------------------------------------
// GEMM2: [N][64] @ [64][32], scaled by dinv.  8 rows/block.
// ---------------------------------------------------------------------------
__global__ __launch_bounds__(256) void gemm2_kernel(const float* __restrict__ h,
                                                    const float* __restrict__ W,
                                                    const float* __restrict__ dinv,
                                                    float* __restrict__ out) {
    __shared__ float ws[64][32];
    __shared__ float rs[8][64];
    int tid = threadIdx.x;
    int brow = blockIdx.x * 8;
    #pragma unroll
    for (int i = 0; i < 2; ++i) {
        int f = tid + i * 256;
        reinterpret_cast<float4*>(&ws[0][0])[f] = reinterpret_cast<const float4*>(W)[f];
    }
    if (tid < 128) {
        float4 v = reinterpret_cast<const float4*>(h)[(size_t)brow * 16 + tid];
        reinterpret_cast<float4*>(&rs[0][0])[tid] = v;
    }
    __syncthreads();
    int lr = tid >> 5;
    int c = tid & 31;
    float acc = 0.f;
    #pragma unroll
    for (int k = 0; k < 64; ++k) acc += rs[lr][k] * ws[k][c];
    int gr = brow + lr;
    out[(size_t)gr * H2F + c] = acc * dinv[gr];
}

// ---------------------------------------------------------------------------
// GEMM3: [N][32] @ [32][16], scaled by dinv.  16 rows/block.
// ---------------------------------------------------------------------------
__global__ __launch_bounds__(256) void gemm3_kernel(const float* __restrict__ h,
                                                    const float* __restrict__ W,
                                                    const float* __restrict__ dinv,
                                                    float* __restrict__ out) {
    __shared__ float ws[32][16];
    __shared__ float rs[16][32];
    int tid = threadIdx.x;
    int brow = blockIdx.x * 16;
    if (tid < 128) {
        reinterpret_cast<float4*>(&ws[0][0])[tid] = reinterpret_cast<const float4*>(W)[tid];
    } else {
        int t = tid - 128;
        float4 v = reinterpret_cast<const float4*>(h)[(size_t)brow * 8 + t];
        reinterpret_cast<float4*>(&rs[0][0])[t] = v;
    }
    __syncthreads();
    int lr = tid >> 4;
    int c = tid & 15;
    float acc = 0.f;
    #pragma unroll
    for (int k = 0; k < 32; ++k) acc += rs[lr][k] * ws[k][c];
    int gr = brow + lr;
    out[(size_t)gr * NCF + c] = acc * dinv[gr];
}

// ---------------------------------------------------------------------------
// Aggregate: out[n][f] = act( dinv[n] * (sum_{src in CSR[n]} h[src][f] + h[n][f]) + b[f] )
// 4-wide unrolled gather for MLP (memory-level parallelism).
// ---------------------------------------------------------------------------
template <int F, bool RELU, bool LSM>
__global__ __launch_bounds__(256) void aggregate_kernel(const float* __restrict__ h,
                                                        const int* __restrict__ row_ptr,
                                                        const int* __restrict__ col,
                                                        const float* __restrict__ dinv,
                                                        const float* __restrict__ bias,
                                                        float* __restrict__ out) {
    int tid = blockIdx.x * 256 + threadIdx.x;
    int n = tid / F;
    int f = tid % F;
    if (n >= N_NODES) return;
    int beg = row_ptr[n];
    int end = row_ptr[n + 1];
    float sum = h[(size_t)n * F + f];   // self-loop term (h already scaled by dinv)
    int j = beg;
    for (; j + 3 < end; j += 4) {
        int c0 = col[j], c1 = col[j + 1], c2 = col[j + 2], c3 = col[j + 3];
        float s0 = h[(size_t)c0 * F + f];
        float s1 = h[(size_t)c1 * F + f];
        float s2 = h[(size_t)c2 * F + f];
        float s3 = h[(size_t)c3 * F + f];
        sum += (s0 + s1) + (s2 + s3);
    }
    for (; j < end; ++j) sum += h[(size_t)col[j] * F + f];

    float val = sum * dinv[n] + bias[f];
    if (RELU) val = fmaxf(val, 0.f);
    if (LSM) {
        float m = val;
        #pragma unroll
        for (int o = 1; o < F; o <<= 1) m = fmaxf(m, __shfl_xor(m, o));
        float ex = expf(val - m);
        float s = ex;
        #pragma unroll
        for (int o = 1; o < F; o <<= 1) s += __shfl_xor(s, o);
        val = val - m - logf(s);
    }
    out[(size_t)n * F + f] = val;
}

// ---------------------------------------------------------------------------
extern "C" void kernel_launch(void* const* d_in, const int* in_sizes, int n_in,
                              void* d_out, int out_size, void* d_ws, size_t ws_size,
                              hipStream_t stream) {
    const float* x  = (const float*)d_in[0];
    const int*   ei = (const int*)d_in[1];
    const float* W1 = (const float*)d_in[2];
    const float* b1 = (const float*)d_in[3];
    const float* W2 = (const float*)d_in[4];
    const float* b2 = (const float*)d_in[5];
    const float* W3 = (const float*)d_in[6];
    const float* b3 = (const float*)d_in[7];
    float* out = (float*)d_out;

    const int* src = ei;              // edge_index[0]
    const int* dst = ei + N_EDGES;    // edge_index[1]

    char* ws = (char*)d_ws;
    size_t off = 0;
    auto alloc = [&](size_t bytes) -> void* {
        void* p = ws + off;
        off += (bytes + 255) & ~(size_t)255;
        return p;
    };
    int*   row_ptr = (int*)alloc((size_t)(N_NODES + 1) * 4);
    float* dinv    = (float*)alloc((size_t)N_NODES * 4);
    int*   col     = (int*)alloc((size_t)N_EDGES * 4);
    float* bufA    = (float*)alloc((size_t)N_NODES * 64 * 4);
    float* bufB    = (float*)alloc((size_t)N_NODES * 64 * 4);
    int*   bcnt    = (int*)alloc((size_t)NB * 4);
    int*   boff    = (int*)alloc((size_t)(NB + 1) * 4);
    int*   bcur    = (int*)alloc((size_t)NB * 4);
    int*   ebuf    = (int*)bufA;      // alias: CSR build finishes before gemm1 writes bufA

    hipMemsetAsync(bcnt, 0, (size_t)NB * 4, stream);
    bhist_kernel<<<256, 256, 0, stream>>>(dst, bcnt);
    bscan_kernel<<<1, 1024, 0, stream>>>(bcnt, boff, bcur, row_ptr);
    bscatter_kernel<<<(N_EDGES + 255) / 256, 256, 0, stream>>>(src, dst, bcur, ebuf);
    bbuild_kernel<<<NB, 256, 0, stream>>>(ebuf, boff, row_ptr, col, dinv);

    // Layer 1: x @ W1 (scaled, bf16 MFMA) -> bufA ; aggregate+bias+relu -> bufB
    gemm1_mfma<<<(N_NODES + 127) / 128, 256, 0, stream>>>(x, W1, dinv, bufA);
    aggregate_kernel<64, true, false><<<(N_NODES * 64) / 256, 256, 0, stream>>>(
        bufA, row_ptr, col, dinv, b1, bufB);

    // Layer 2: bufB @ W2 (scaled) -> bufA ; aggregate+bias+relu -> bufB
    gemm2_kernel<<<N_NODES / 8, 256, 0, stream>>>(bufB, W2, dinv, bufA);
    aggregate_kernel<32, true, false><<<(N_NODES * 32) / 256, 256, 0, stream>>>(
        bufA, row_ptr, col, dinv, b2, bufB);

    // Layer 3: bufB @ W3 (scaled) -> bufA ; aggregate+bias+log_softmax -> out
    gemm3_kernel<<<N_NODES / 16, 256, 0, stream>>>(bufB, W3, dinv, bufA);
    aggregate_kernel<16, false, true><<<(N_NODES * 16) / 256, 256, 0, stream>>>(
        bufA, row_ptr, col, dinv, b3, out);
}

// Round 10
// 569.578 us; speedup vs baseline: 1.5629x; 1.5629x over previous
//
#include <hip/hip_runtime.h>
#include <hip/hip_bf16.h>
#include <cstdint>
#include <cstddef>

#define N_NODES 100000
#define N_EDGES 1600000
#define F_IN 512
#define H1F 64
#define H2F 32
#define NCF 16
#define NB 782            // buckets of 128 nodes: ceil(100000/128)
#define NBLK 128          // edge chunks for counting sort
#define CHUNK 12500       // N_EDGES / NBLK exactly

typedef __attribute__((ext_vector_type(8))) short bf16x8;
typedef __attribute__((ext_vector_type(4))) float f32x4;

__device__ inline short f2bf(float f) {
    // RNE f32 -> bf16 (inputs are finite, no NaN handling needed)
    uint32_t u = __builtin_bit_cast(uint32_t, f);
    return (short)((u + 0x7FFF + ((u >> 16) & 1)) >> 16);
}

// ---------------------------------------------------------------------------
// C1: per-chunk bucket histogram (LDS only) -> mat[blk][bucket]
// ---------------------------------------------------------------------------
__global__ __launch_bounds__(256) void count_kernel(const int* __restrict__ dst,
                                                    int* __restrict__ mat) {
    __shared__ int lh[NB];
    for (int i = threadIdx.x; i < NB; i += 256) lh[i] = 0;
    __syncthreads();
    int base = blockIdx.x * CHUNK;
    for (int j = base + threadIdx.x; j < base + CHUNK; j += 256)
        atomicAdd(&lh[dst[j] >> 7], 1);
    __syncthreads();
    for (int i = threadIdx.x; i < NB; i += 256)
        mat[blockIdx.x * NB + i] = lh[i];
}

// ---------------------------------------------------------------------------
// C2: per bucket, exclusive scan of the NBLK block-counts; bucket totals.
// ---------------------------------------------------------------------------
__global__ __launch_bounds__(NBLK) void colscan_kernel(int* __restrict__ mat,
                                                       int* __restrict__ total) {
    __shared__ int s[NBLK];
    int b = blockIdx.x;
    int t = threadIdx.x;
    int v = mat[t * NB + b];
    s[t] = v;
    __syncthreads();
    for (int o = 1; o < NBLK; o <<= 1) {
        int a = (t >= o) ? s[t - o] : 0;
        __syncthreads();
        s[t] += a;
        __syncthreads();
    }
    mat[t * NB + b] = s[t] - v;          // exclusive prefix across blocks
    if (t == NBLK - 1) total[b] = s[t];  // bucket total
}

// ---------------------------------------------------------------------------
// C3: exclusive scan of total[NB] -> boff[NB+1]; row_ptr[N]=E
// ---------------------------------------------------------------------------
__global__ __launch_bounds__(1024) void bscan_kernel(const int* __restrict__ total,
                                                     int* __restrict__ boff,
                                                     int* __restrict__ row_ptr) {
    __shared__ int s[1024];
    int t = threadIdx.x;
    int v = (t < NB) ? total[t] : 0;
    s[t] = v;
    __syncthreads();
    for (int o = 1; o < 1024; o <<= 1) {
        int a = (t >= o) ? s[t - o] : 0;
        __syncthreads();
        s[t] += a;
        __syncthreads();
    }
    if (t < NB) boff[t] = s[t] - v;
    if (t == 0) {
        boff[NB] = N_EDGES;
        row_ptr[N_NODES] = N_EDGES;
    }
}

// ---------------------------------------------------------------------------
// C4: placement pass — LDS cursors seeded from boff + mat (no global atomics).
// Each ebuf line is written by exactly one block (one XCD) and fills fully.
// ---------------------------------------------------------------------------
__global__ __launch_bounds__(256) void place_kernel(const int* __restrict__ src,
                                                    const int* __restrict__ dst,
                                                    const int* __restrict__ boff,
                                                    const int* __restrict__ mat,
                                                    int* __restrict__ ebuf) {
    __shared__ int lcur[NB];
    for (int i = threadIdx.x; i < NB; i += 256)
        lcur[i] = boff[i] + mat[blockIdx.x * NB + i];
    __syncthreads();
    int base = blockIdx.x * CHUNK;
    for (int j = base + threadIdx.x; j < base + CHUNK; j += 256) {
        int d = dst[j];
        int b = d >> 7;
        int pos = atomicAdd(&lcur[b], 1);   // LDS atomic, ~16/bucket/block
        ebuf[pos] = src[j] | ((d & 127) << 17);
    }
}

// ---------------------------------------------------------------------------
// C5: per-bucket fine CSR build entirely in LDS; col writes confined to the
// bucket's contiguous ~8 KB segment (L2-resident). Also row_ptr + dinv.
// ---------------------------------------------------------------------------
__global__ __launch_bounds__(256) void bbuild_kernel(const int* __restrict__ ebuf,
                                                     const int* __restrict__ boff,
                                                     int* __restrict__ row_ptr,
                                                     int* __restrict__ col,
                                                     float* __restrict__ dinv) {
    __shared__ int lcnt[128], lexc[128];
    int b = blockIdx.x;
    int beg = boff[b], end = boff[b + 1];
    int t = threadIdx.x;
    if (t < 128) lcnt[t] = 0;
    __syncthreads();
    for (int j = beg + t; j < end; j += 256)
        atomicAdd(&lcnt[(ebuf[j] >> 17) & 127], 1);
    __syncthreads();
    if (t < 128) lexc[t] = lcnt[t];
    __syncthreads();
    for (int o = 1; o < 128; o <<= 1) {
        int a = (t < 128 && t >= o) ? lexc[t - o] : 0;
        __syncthreads();
        if (t < 128) lexc[t] += a;
        __syncthreads();
    }
    int node0 = b << 7;
    if (t < 128) {
        int n = node0 + t;
        if (n < N_NODES) {
            int ex = lexc[t] - lcnt[t];        // exclusive
            row_ptr[n] = beg + ex;
            dinv[n] = rsqrtf((float)(lcnt[t] + 1));
            lexc[t] = ex;                      // reuse as cursor
        }
    }
    __syncthreads();
    for (int j = beg + t; j < end; j += 256) {
        int v = ebuf[j];
        int li = (v >> 17) & 127;
        int p = atomicAdd(&lexc[li], 1);
        col[beg + p] = v & 0x1FFFF;
    }
}

// ---------------------------------------------------------------------------
// GEMM1 (bf16 MFMA): out[r][c] = dinv[r] * sum_k x[r][k]*W[k][c]
// M=100000, K=512, N=64. BM=128, BK=32, 256 threads = 4 waves,
// wave-tile 32 rows x 64 cols, mfma_f32_16x16x32_bf16, f32 accum.
// ---------------------------------------------------------------------------
__global__ __launch_bounds__(256) void gemm1_mfma(const float* __restrict__ x,
                                                  const float* __restrict__ W,
                                                  const float* __restrict__ dinv,
                                                  float* __restrict__ out) {
    __shared__ short As[2][4096];   // [kg]*1024 + (r ^ (kg<<2))*8 + i
    __shared__ short Bs[2][2048];   // byte: c*64 + ((kglocal*16) ^ ((c&3)<<4))
    const int tid = threadIdx.x;
    const int L = tid & 63;
    const int w = tid >> 6;          // wave 0..3
    const int brow = blockIdx.x * 128;

    f32x4 acc[2][4] = {};

    auto stageA = [&](int kt, int buf) {
        #pragma unroll
        for (int h = 0; h < 2; ++h) {
            int r  = (tid >> 2) + h * 64;   // 0..127
            int kg = tid & 3;               // k-group of 8
            int gr = brow + r;
            float4 v0 = make_float4(0.f, 0.f, 0.f, 0.f);
            float4 v1 = make_float4(0.f, 0.f, 0.f, 0.f);
            if (gr < N_NODES) {
                const float* p = &x[(size_t)gr * F_IN + kt * 32 + kg * 8];
                v0 = *reinterpret_cast<const float4*>(p);
                v1 = *reinterpret_cast<const float4*>(p + 4);
            }
            short t8[8] = {f2bf(v0.x), f2bf(v0.y), f2bf(v0.z), f2bf(v0.w),
                           f2bf(v1.x), f2bf(v1.y), f2bf(v1.z), f2bf(v1.w)};
            *reinterpret_cast<bf16x8*>(&As[buf][kg * 1024 + (r ^ (kg << 2)) * 8]) =
                *reinterpret_cast<bf16x8*>(t8);
        }
    };
    auto stageB = [&](int kt, int buf) {
        int k0 = kt * 32 + w * 8;
        short t8[8];
        #pragma unroll
        for (int i = 0; i < 8; ++i) t8[i] = f2bf(W[(size_t)(k0 + i) * H1F + L]);
        int byteoff = L * 64 + ((w * 16) ^ ((L & 3) << 4));
        *reinterpret_cast<bf16x8*>((char*)Bs[buf] + byteoff) =
            *reinterpret_cast<bf16x8*>(t8);
    };
    auto compute = [&](int buf) {
        const int kg = L >> 4;            // 0..3  (k = kg*8 + i)
        const int lr = L & 15;
        int r0 = w * 32 + lr;
        int r1 = r0 + 16;
        bf16x8 a0 = *reinterpret_cast<bf16x8*>(&As[buf][kg * 1024 + (r0 ^ (kg << 2)) * 8]);
        bf16x8 a1 = *reinterpret_cast<bf16x8*>(&As[buf][kg * 1024 + (r1 ^ (kg << 2)) * 8]);
        #pragma unroll
        for (int ni = 0; ni < 4; ++ni) {
            int c = ni * 16 + lr;
            bf16x8 b = *reinterpret_cast<bf16x8*>(
                (char*)Bs[buf] + c * 64 + ((kg * 16) ^ ((c & 3) << 4)));
            acc[0][ni] = __builtin_amdgcn_mfma_f32_16x16x32_bf16(a0, b, acc[0][ni], 0, 0, 0);
            acc[1][ni] = __builtin_amdgcn_mfma_f32_16x16x32_bf16(a1, b, acc[1][ni], 0, 0, 0);
        }
    };

    stageA(0, 0);
    stageB(0, 0);
    __syncthreads();
    for (int kt = 0; kt < 16; ++kt) {
        int cur = kt & 1;
        if (kt < 15) {
            stageA(kt + 1, cur ^ 1);
            stageB(kt + 1, cur ^ 1);
        }
        compute(cur);
        __syncthreads();
    }

    // epilogue: D mapping col=lane&15, row=(lane>>4)*4+i  [m89-verified]
    #pragma unroll
    for (int mi = 0; mi < 2; ++mi) {
        #pragma unroll
        for (int i = 0; i < 4; ++i) {
            int row = brow + w * 32 + mi * 16 + (L >> 4) * 4 + i;
            if (row < N_NODES) {
                float dv = dinv[row];
                #pragma unroll
                for (int ni = 0; ni < 4; ++ni)
                    out[(size_t)row * H1F + ni * 16 + (L & 15)] = acc[mi][ni][i] * dv;
            }
        }
    }
}

// ---------------------------------------------------------------------------
// GEMM2: [N][64] @ [64][32], scaled by dinv.  8 rows/block.
// ---------------------------------------------------------------------------
__global__ __launch_bounds__(256) void gemm2_kernel(const float* __restrict__ h,
                                                    const float* __restrict__ W,
                                                    const float* __restrict__ dinv,
                                                    float* __restrict__ out) {
    __shared__ float ws[64][32];
    __shared__ float rs[8][64];
    int tid = threadIdx.x;
    int brow = blockIdx.x * 8;
    #pragma unroll
    for (int i = 0; i < 2; ++i) {
        int f = tid + i * 256;
        reinterpret_cast<float4*>(&ws[0][0])[f] = reinterpret_cast<const float4*>(W)[f];
    }
    if (tid < 128) {
        float4 v = reinterpret_cast<const float4*>(h)[(size_t)brow * 16 + tid];
        reinterpret_cast<float4*>(&rs[0][0])[tid] = v;
    }
    __syncthreads();
    int lr = tid >> 5;
    int c = tid & 31;
    float acc = 0.f;
    #pragma unroll
    for (int k = 0; k < 64; ++k) acc += rs[lr][k] * ws[k][c];
    int gr = brow + lr;
    out[(size_t)gr * H2F + c] = acc * dinv[gr];
}

// ---------------------------------------------------------------------------
// GEMM3: [N][32] @ [32][16], scaled by dinv.  16 rows/block.
// ---------------------------------------------------------------------------
__global__ __launch_bounds__(256) void gemm3_kernel(const float* __restrict__ h,
                                                    const float* __restrict__ W,
                                                    const float* __restrict__ dinv,
                                                    float* __restrict__ out) {
    __shared__ float ws[32][16];
    __shared__ float rs[16][32];
    int tid = threadIdx.x;
    int brow = blockIdx.x * 16;
    if (tid < 128) {
        reinterpret_cast<float4*>(&ws[0][0])[tid] = reinterpret_cast<const float4*>(W)[tid];
    } else {
        int t = tid - 128;
        float4 v = reinterpret_cast<const float4*>(h)[(size_t)brow * 8 + t];
        reinterpret_cast<float4*>(&rs[0][0])[t] = v;
    }
    __syncthreads();
    int lr = tid >> 4;
    int c = tid & 15;
    float acc = 0.f;
    #pragma unroll
    for (int k = 0; k < 32; ++k) acc += rs[lr][k] * ws[k][c];
    int gr = brow + lr;
    out[(size_t)gr * NCF + c] = acc * dinv[gr];
}

// ---------------------------------------------------------------------------
// Aggregate: out[n][f] = act( dinv[n] * (sum_{src in CSR[n]} h[src][f] + h[n][f]) + b[f] )
// 4-wide unrolled gather for MLP (memory-level parallelism).
// ---------------------------------------------------------------------------
template <int F, bool RELU, bool LSM>
__global__ __launch_bounds__(256) void aggregate_kernel(const float* __restrict__ h,
                                                        const int* __restrict__ row_ptr,
                                                        const int* __restrict__ col,
                                                        const float* __restrict__ dinv,
                                                        const float* __restrict__ bias,
                                                        float* __restrict__ out) {
    int tid = blockIdx.x * 256 + threadIdx.x;
    int n = tid / F;
    int f = tid % F;
    if (n >= N_NODES) return;
    int beg = row_ptr[n];
    int end = row_ptr[n + 1];
    float sum = h[(size_t)n * F + f];   // self-loop term (h already scaled by dinv)
    int j = beg;
    for (; j + 3 < end; j += 4) {
        int c0 = col[j], c1 = col[j + 1], c2 = col[j + 2], c3 = col[j + 3];
        float s0 = h[(size_t)c0 * F + f];
        float s1 = h[(size_t)c1 * F + f];
        float s2 = h[(size_t)c2 * F + f];
        float s3 = h[(size_t)c3 * F + f];
        sum += (s0 + s1) + (s2 + s3);
    }
    for (; j < end; ++j) sum += h[(size_t)col[j] * F + f];

    float val = sum * dinv[n] + bias[f];
    if (RELU) val = fmaxf(val, 0.f);
    if (LSM) {
        float m = val;
        #pragma unroll
        for (int o = 1; o < F; o <<= 1) m = fmaxf(m, __shfl_xor(m, o));
        float ex = expf(val - m);
        float s = ex;
        #pragma unroll
        for (int o = 1; o < F; o <<= 1) s += __shfl_xor(s, o);
        val = val - m - logf(s);
    }
    out[(size_t)n * F + f] = val;
}

// ---------------------------------------------------------------------------
extern "C" void kernel_launch(void* const* d_in, const int* in_sizes, int n_in,
                              void* d_out, int out_size, void* d_ws, size_t ws_size,
                              hipStream_t stream) {
    const float* x  = (const float*)d_in[0];
    const int*   ei = (const int*)d_in[1];
    const float* W1 = (const float*)d_in[2];
    const float* b1 = (const float*)d_in[3];
    const float* W2 = (const float*)d_in[4];
    const float* b2 = (const float*)d_in[5];
    const float* W3 = (const float*)d_in[6];
    const float* b3 = (const float*)d_in[7];
    float* out = (float*)d_out;

    const int* src = ei;              // edge_index[0]
    const int* dst = ei + N_EDGES;    // edge_index[1]

    char* ws = (char*)d_ws;
    size_t off = 0;
    auto alloc = [&](size_t bytes) -> void* {
        void* p = ws + off;
        off += (bytes + 255) & ~(size_t)255;
        return p;
    };
    int*   row_ptr = (int*)alloc((size_t)(N_NODES + 1) * 4);
    float* dinv    = (float*)alloc((size_t)N_NODES * 4);
    int*   col     = (int*)alloc((size_t)N_EDGES * 4);
    float* bufA    = (float*)alloc((size_t)N_NODES * 64 * 4);
    float* bufB    = (float*)alloc((size_t)N_NODES * 64 * 4);
    int*   mat     = (int*)alloc((size_t)NBLK * NB * 4);
    int*   total   = (int*)alloc((size_t)NB * 4);
    int*   boff    = (int*)alloc((size_t)(NB + 1) * 4);
    int*   ebuf    = (int*)bufA;      // alias: CSR build finishes before gemm1 writes bufA

    count_kernel<<<NBLK, 256, 0, stream>>>(dst, mat);
    colscan_kernel<<<NB, NBLK, 0, stream>>>(mat, total);
    bscan_kernel<<<1, 1024, 0, stream>>>(total, boff, row_ptr);
    place_kernel<<<NBLK, 256, 0, stream>>>(src, dst, boff, mat, ebuf);
    bbuild_kernel<<<NB, 256, 0, stream>>>(ebuf, boff, row_ptr, col, dinv);

    // Layer 1: x @ W1 (scaled, bf16 MFMA) -> bufA ; aggregate+bias+relu -> bufB
    gemm1_mfma<<<(N_NODES + 127) / 128, 256, 0, stream>>>(x, W1, dinv, bufA);
    aggregate_kernel<64, true, false><<<(N_NODES * 64) / 256, 256, 0, stream>>>(
        bufA, row_ptr, col, dinv, b1, bufB);

    // Layer 2: bufB @ W2 (scaled) -> bufA ; aggregate+bias+relu -> bufB
    gemm2_kernel<<<N_NODES / 8, 256, 0, stream>>>(bufB, W2, dinv, bufA);
    aggregate_kernel<32, true, false><<<(N_NODES * 32) / 256, 256, 0, stream>>>(
        bufA, row_ptr, col, dinv, b2, bufB);

    // Layer 3: bufB @ W3 (scaled) -> bufA ; aggregate+bias+log_softmax -> out
    gemm3_kernel<<<N_NODES / 16, 256, 0, stream>>>(bufB, W3, dinv, bufA);
    aggregate_kernel<16, false, true><<<(N_NODES * 16) / 256, 256, 0, stream>>>(
        bufA, row_ptr, col, dinv, b3, out);
}

// Round 11
// 554.467 us; speedup vs baseline: 1.6055x; 1.0273x over previous
//
#include <hip/hip_runtime.h>
#include <hip/hip_bf16.h>
#include <cstdint>
#include <cstddef>

#define N_NODES 100000
#define N_EDGES 1600000
#define F_IN 512
#define H1F 64
#define H2F 32
#define NCF 16
#define NB 782            // buckets of 128 nodes: ceil(100000/128)
#define NBLK 128          // edge chunks for counting sort
#define CHUNK 12500       // N_EDGES / NBLK exactly

typedef __attribute__((ext_vector_type(8))) short bf16x8;
typedef __attribute__((ext_vector_type(8))) unsigned short ushort8;
typedef __attribute__((ext_vector_type(4))) float f32x4;

__device__ inline short f2bf(float f) {
    // RNE f32 -> bf16 (inputs are finite, no NaN handling needed)
    uint32_t u = __builtin_bit_cast(uint32_t, f);
    return (short)((u + 0x7FFF + ((u >> 16) & 1)) >> 16);
}
__device__ inline float bf2f(unsigned short u) {
    uint32_t x = ((uint32_t)u) << 16;
    return __builtin_bit_cast(float, x);
}

// ---------------------------------------------------------------------------
// C1: per-chunk bucket histogram (LDS only) -> mat[blk][bucket]
// ---------------------------------------------------------------------------
__global__ __launch_bounds__(256) void count_kernel(const int* __restrict__ dst,
                                                    int* __restrict__ mat) {
    __shared__ int lh[NB];
    for (int i = threadIdx.x; i < NB; i += 256) lh[i] = 0;
    __syncthreads();
    int base = blockIdx.x * CHUNK;
    for (int j = base + threadIdx.x; j < base + CHUNK; j += 256)
        atomicAdd(&lh[dst[j] >> 7], 1);
    __syncthreads();
    for (int i = threadIdx.x; i < NB; i += 256)
        mat[blockIdx.x * NB + i] = lh[i];
}

// ---------------------------------------------------------------------------
// C2: per bucket, exclusive scan of the NBLK block-counts; bucket totals.
// ---------------------------------------------------------------------------
__global__ __launch_bounds__(NBLK) void colscan_kernel(int* __restrict__ mat,
                                                       int* __restrict__ total) {
    __shared__ int s[NBLK];
    int b = blockIdx.x;
    int t = threadIdx.x;
    int v = mat[t * NB + b];
    s[t] = v;
    __syncthreads();
    for (int o = 1; o < NBLK; o <<= 1) {
        int a = (t >= o) ? s[t - o] : 0;
        __syncthreads();
        s[t] += a;
        __syncthreads();
    }
    mat[t * NB + b] = s[t] - v;          // exclusive prefix across blocks
    if (t == NBLK - 1) total[b] = s[t];  // bucket total
}

// ---------------------------------------------------------------------------
// C3: exclusive scan of total[NB] -> boff[NB+1]; row_ptr[N]=E
// ---------------------------------------------------------------------------
__global__ __launch_bounds__(1024) void bscan_kernel(const int* __restrict__ total,
                                                     int* __restrict__ boff,
                                                     int* __restrict__ row_ptr) {
    __shared__ int s[1024];
    int t = threadIdx.x;
    int v = (t < NB) ? total[t] : 0;
    s[t] = v;
    __syncthreads();
    for (int o = 1; o < 1024; o <<= 1) {
        int a = (t >= o) ? s[t - o] : 0;
        __syncthreads();
        s[t] += a;
        __syncthreads();
    }
    if (t < NB) boff[t] = s[t] - v;
    if (t == 0) {
        boff[NB] = N_EDGES;
        row_ptr[N_NODES] = N_EDGES;
    }
}

// ---------------------------------------------------------------------------
// C4: placement pass — LDS cursors seeded from boff + mat (no global atomics).
// ---------------------------------------------------------------------------
__global__ __launch_bounds__(256) void place_kernel(const int* __restrict__ src,
                                                    const int* __restrict__ dst,
                                                    const int* __restrict__ boff,
                                                    const int* __restrict__ mat,
                                                    int* __restrict__ ebuf) {
    __shared__ int lcur[NB];
    for (int i = threadIdx.x; i < NB; i += 256)
        lcur[i] = boff[i] + mat[blockIdx.x * NB + i];
    __syncthreads();
    int base = blockIdx.x * CHUNK;
    for (int j = base + threadIdx.x; j < base + CHUNK; j += 256) {
        int d = dst[j];
        int b = d >> 7;
        int pos = atomicAdd(&lcur[b], 1);   // LDS atomic, ~16/bucket/block
        ebuf[pos] = src[j] | ((d & 127) << 17);
    }
}

// ---------------------------------------------------------------------------
// C5: per-bucket fine CSR build entirely in LDS.
// ---------------------------------------------------------------------------
__global__ __launch_bounds__(256) void bbuild_kernel(const int* __restrict__ ebuf,
                                                     const int* __restrict__ boff,
                                                     int* __restrict__ row_ptr,
                                                     int* __restrict__ col,
                                                     float* __restrict__ dinv) {
    __shared__ int lcnt[128], lexc[128];
    int b = blockIdx.x;
    int beg = boff[b], end = boff[b + 1];
    int t = threadIdx.x;
    if (t < 128) lcnt[t] = 0;
    __syncthreads();
    for (int j = beg + t; j < end; j += 256)
        atomicAdd(&lcnt[(ebuf[j] >> 17) & 127], 1);
    __syncthreads();
    if (t < 128) lexc[t] = lcnt[t];
    __syncthreads();
    for (int o = 1; o < 128; o <<= 1) {
        int a = (t < 128 && t >= o) ? lexc[t - o] : 0;
        __syncthreads();
        if (t < 128) lexc[t] += a;
        __syncthreads();
    }
    int node0 = b << 7;
    if (t < 128) {
        int n = node0 + t;
        if (n < N_NODES) {
            int ex = lexc[t] - lcnt[t];        // exclusive
            row_ptr[n] = beg + ex;
            dinv[n] = rsqrtf((float)(lcnt[t] + 1));
            lexc[t] = ex;                      // reuse as cursor
        }
    }
    __syncthreads();
    for (int j = beg + t; j < end; j += 256) {
        int v = ebuf[j];
        int li = (v >> 17) & 127;
        int p = atomicAdd(&lexc[li], 1);
        col[beg + p] = v & 0x1FFFF;
    }
}

// ---------------------------------------------------------------------------
// GEMM1 (bf16 MFMA): out[r][c] = bf16( dinv[r] * sum_k x[r][k]*W[k][c] )
// ---------------------------------------------------------------------------
__global__ __launch_bounds__(256) void gemm1_mfma(const float* __restrict__ x,
                                                  const float* __restrict__ W,
                                                  const float* __restrict__ dinv,
                                                  unsigned short* __restrict__ out) {
    __shared__ short As[2][4096];   // [kg]*1024 + (r ^ (kg<<2))*8 + i
    __shared__ short Bs[2][2048];   // byte: c*64 + ((kglocal*16) ^ ((c&3)<<4))
    const int tid = threadIdx.x;
    const int L = tid & 63;
    const int w = tid >> 6;          // wave 0..3
    const int brow = blockIdx.x * 128;

    f32x4 acc[2][4] = {};

    auto stageA = [&](int kt, int buf) {
        #pragma unroll
        for (int h = 0; h < 2; ++h) {
            int r  = (tid >> 2) + h * 64;   // 0..127
            int kg = tid & 3;               // k-group of 8
            int gr = brow + r;
            float4 v0 = make_float4(0.f, 0.f, 0.f, 0.f);
            float4 v1 = make_float4(0.f, 0.f, 0.f, 0.f);
            if (gr < N_NODES) {
                const float* p = &x[(size_t)gr * F_IN + kt * 32 + kg * 8];
                v0 = *reinterpret_cast<const float4*>(p);
                v1 = *reinterpret_cast<const float4*>(p + 4);
            }
            short t8[8] = {f2bf(v0.x), f2bf(v0.y), f2bf(v0.z), f2bf(v0.w),
                           f2bf(v1.x), f2bf(v1.y), f2bf(v1.z), f2bf(v1.w)};
            *reinterpret_cast<bf16x8*>(&As[buf][kg * 1024 + (r ^ (kg << 2)) * 8]) =
                *reinterpret_cast<bf16x8*>(t8);
        }
    };
    auto stageB = [&](int kt, int buf) {
        int k0 = kt * 32 + w * 8;
        short t8[8];
        #pragma unroll
        for (int i = 0; i < 8; ++i) t8[i] = f2bf(W[(size_t)(k0 + i) * H1F + L]);
        int byteoff = L * 64 + ((w * 16) ^ ((L & 3) << 4));
        *reinterpret_cast<bf16x8*>((char*)Bs[buf] + byteoff) =
            *reinterpret_cast<bf16x8*>(t8);
    };
    auto compute = [&](int buf) {
        const int kg = L >> 4;            // 0..3  (k = kg*8 + i)
        const int lr = L & 15;
        int r0 = w * 32 + lr;
        int r1 = r0 + 16;
        bf16x8 a0 = *reinterpret_cast<bf16x8*>(&As[buf][kg * 1024 + (r0 ^ (kg << 2)) * 8]);
        bf16x8 a1 = *reinterpret_cast<bf16x8*>(&As[buf][kg * 1024 + (r1 ^ (kg << 2)) * 8]);
        #pragma unroll
        for (int ni = 0; ni < 4; ++ni) {
            int c = ni * 16 + lr;
            bf16x8 b = *reinterpret_cast<bf16x8*>(
                (char*)Bs[buf] + c * 64 + ((kg * 16) ^ ((c & 3) << 4)));
            acc[0][ni] = __builtin_amdgcn_mfma_f32_16x16x32_bf16(a0, b, acc[0][ni], 0, 0, 0);
            acc[1][ni] = __builtin_amdgcn_mfma_f32_16x16x32_bf16(a1, b, acc[1][ni], 0, 0, 0);
        }
    };

    stageA(0, 0);
    stageB(0, 0);
    __syncthreads();
    for (int kt = 0; kt < 16; ++kt) {
        int cur = kt & 1;
        if (kt < 15) {
            stageA(kt + 1, cur ^ 1);
            stageB(kt + 1, cur ^ 1);
        }
        compute(cur);
        __syncthreads();
    }

    // epilogue: D mapping col=lane&15, row=(lane>>4)*4+i  [m89-verified]
    #pragma unroll
    for (int mi = 0; mi < 2; ++mi) {
        #pragma unroll
        for (int i = 0; i < 4; ++i) {
            int row = brow + w * 32 + mi * 16 + (L >> 4) * 4 + i;
            if (row < N_NODES) {
                float dv = dinv[row];
                #pragma unroll
                for (int ni = 0; ni < 4; ++ni)
                    out[(size_t)row * H1F + ni * 16 + (L & 15)] =
                        (unsigned short)f2bf(acc[mi][ni][i] * dv);
            }
        }
    }
}

// ---------------------------------------------------------------------------
// GEMM2: bf16[N][64] @ f32[64][32] -> bf16, scaled by dinv.  8 rows/block.
// ---------------------------------------------------------------------------
__global__ __launch_bounds__(256) void gemm2_kernel(const unsigned short* __restrict__ h,
                                                    const float* __restrict__ W,
                                                    const float* __restrict__ dinv,
                                                    unsigned short* __restrict__ out) {
    __shared__ float ws[64][32];
    __shared__ float rs[8][64];
    int tid = threadIdx.x;
    int brow = blockIdx.x * 8;
    #pragma unroll
    for (int i = 0; i < 2; ++i) {
        int f = tid + i * 256;   // 512 float4 of W
        reinterpret_cast<float4*>(&ws[0][0])[f] = reinterpret_cast<const float4*>(W)[f];
    }
    if (tid < 64) {
        // 8 rows x 64 = 512 bf16 = 64 x ushort8, contiguous
        ushort8 v = reinterpret_cast<const ushort8*>(h + (size_t)brow * 64)[tid];
        #pragma unroll
        for (int j = 0; j < 8; ++j) (&rs[0][0])[tid * 8 + j] = bf2f(v[j]);
    }
    __syncthreads();
    int lr = tid >> 5;
    int c = tid & 31;
    float acc = 0.f;
    #pragma unroll
    for (int k = 0; k < 64; ++k) acc += rs[lr][k] * ws[k][c];
    int gr = brow + lr;
    out[(size_t)gr * H2F + c] = (unsigned short)f2bf(acc * dinv[gr]);
}

// ---------------------------------------------------------------------------
// GEMM3: bf16[N][32] @ f32[32][16] -> bf16, scaled by dinv.  16 rows/block.
// ---------------------------------------------------------------------------
__global__ __launch_bounds__(256) void gemm3_kernel(const unsigned short* __restrict__ h,
                                                    const float* __restrict__ W,
                                                    const float* __restrict__ dinv,
                                                    unsigned short* __restrict__ out) {
    __shared__ float ws[32][16];
    __shared__ float rs[16][32];
    int tid = threadIdx.x;
    int brow = blockIdx.x * 16;
    if (tid < 128) {
        reinterpret_cast<float4*>(&ws[0][0])[tid] = reinterpret_cast<const float4*>(W)[tid];
    } else if (tid < 192) {
        int t = tid - 128;   // 64 x ushort8 of 16 rows x 32 bf16
        ushort8 v = reinterpret_cast<const ushort8*>(h + (size_t)brow * 32)[t];
        #pragma unroll
        for (int j = 0; j < 8; ++j) (&rs[0][0])[t * 8 + j] = bf2f(v[j]);
    }
    __syncthreads();
    int lr = tid >> 4;
    int c = tid & 15;
    float acc = 0.f;
    #pragma unroll
    for (int k = 0; k < 32; ++k) acc += rs[lr][k] * ws[k][c];
    int gr = brow + lr;
    out[(size_t)gr * NCF + c] = (unsigned short)f2bf(acc * dinv[gr]);
}

// ---------------------------------------------------------------------------
// Aggregate (bf16 in): val = dinv[n]*(sum_csr h[src][f] + h[n][f]) + b[f]
// LSM=false: write bf16.  LSM=true: write f32 (final output).
// ---------------------------------------------------------------------------
template <int F, bool RELU, bool LSM>
__global__ __launch_bounds__(256) void aggregate_kernel(const unsigned short* __restrict__ h,
                                                        const int* __restrict__ row_ptr,
                                                        const int* __restrict__ col,
                                                        const float* __restrict__ dinv,
                                                        const float* __restrict__ bias,
                                                        void* __restrict__ outp) {
    int tid = blockIdx.x * 256 + threadIdx.x;
    int n = tid / F;
    int f = tid % F;
    if (n >= N_NODES) return;
    int beg = row_ptr[n];
    int end = row_ptr[n + 1];
    float sum = bf2f(h[(size_t)n * F + f]);   // self-loop (h already dinv-scaled)
    int j = beg;
    for (; j + 3 < end; j += 4) {
        int c0 = col[j], c1 = col[j + 1], c2 = col[j + 2], c3 = col[j + 3];
        float s0 = bf2f(h[(size_t)c0 * F + f]);
        float s1 = bf2f(h[(size_t)c1 * F + f]);
        float s2 = bf2f(h[(size_t)c2 * F + f]);
        float s3 = bf2f(h[(size_t)c3 * F + f]);
        sum += (s0 + s1) + (s2 + s3);
    }
    for (; j < end; ++j) sum += bf2f(h[(size_t)col[j] * F + f]);

    float val = sum * dinv[n] + bias[f];
    if (RELU) val = fmaxf(val, 0.f);
    if (LSM) {
        float m = val;
        #pragma unroll
        for (int o = 1; o < F; o <<= 1) m = fmaxf(m, __shfl_xor(m, o));
        float ex = expf(val - m);
        float s = ex;
        #pragma unroll
        for (int o = 1; o < F; o <<= 1) s += __shfl_xor(s, o);
        val = val - m - logf(s);
        ((float*)outp)[(size_t)n * F + f] = val;
    } else {
        ((unsigned short*)outp)[(size_t)n * F + f] = (unsigned short)f2bf(val);
    }
}

// ---------------------------------------------------------------------------
extern "C" void kernel_launch(void* const* d_in, const int* in_sizes, int n_in,
                              void* d_out, int out_size, void* d_ws, size_t ws_size,
                              hipStream_t stream) {
    const float* x  = (const float*)d_in[0];
    const int*   ei = (const int*)d_in[1];
    const float* W1 = (const float*)d_in[2];
    const float* b1 = (const float*)d_in[3];
    const float* W2 = (const float*)d_in[4];
    const float* b2 = (const float*)d_in[5];
    const float* W3 = (const float*)d_in[6];
    const float* b3 = (const float*)d_in[7];
    float* out = (float*)d_out;

    const int* src = ei;              // edge_index[0]
    const int* dst = ei + N_EDGES;    // edge_index[1]

    char* ws = (char*)d_ws;
    size_t off = 0;
    auto alloc = [&](size_t bytes) -> void* {
        void* p = ws + off;
        off += (bytes + 255) & ~(size_t)255;
        return p;
    };
    int*            row_ptr = (int*)alloc((size_t)(N_NODES + 1) * 4);
    float*          dinv    = (float*)alloc((size_t)N_NODES * 4);
    int*            col     = (int*)alloc((size_t)N_EDGES * 4);
    unsigned short* bufA    = (unsigned short*)alloc((size_t)N_NODES * 64 * 2);
    unsigned short* bufB    = (unsigned short*)alloc((size_t)N_NODES * 64 * 2);
    int*            mat     = (int*)alloc((size_t)NBLK * NB * 4);
    int*            total   = (int*)alloc((size_t)NB * 4);
    int*            boff    = (int*)alloc((size_t)(NB + 1) * 4);
    int*            ebuf    = (int*)bufA;  // alias: 6.4MB < 12.8MB, build precedes gemm1

    count_kernel<<<NBLK, 256, 0, stream>>>(dst, mat);
    colscan_kernel<<<NB, NBLK, 0, stream>>>(mat, total);
    bscan_kernel<<<1, 1024, 0, stream>>>(total, boff, row_ptr);
    place_kernel<<<NBLK, 256, 0, stream>>>(src, dst, boff, mat, ebuf);
    bbuild_kernel<<<NB, 256, 0, stream>>>(ebuf, boff, row_ptr, col, dinv);

    // Layer 1: x @ W1 (scaled, bf16 MFMA) -> bufA ; aggregate+bias+relu -> bufB
    gemm1_mfma<<<(N_NODES + 127) / 128, 256, 0, stream>>>(x, W1, dinv, bufA);
    aggregate_kernel<64, true, false><<<(N_NODES * 64) / 256, 256, 0, stream>>>(
        bufA, row_ptr, col, dinv, b1, bufB);

    // Layer 2: bufB @ W2 (scaled) -> bufA ; aggregate+bias+relu -> bufB
    gemm2_kernel<<<N_NODES / 8, 256, 0, stream>>>(bufB, W2, dinv, bufA);
    aggregate_kernel<32, true, false><<<(N_NODES * 32) / 256, 256, 0, stream>>>(
        bufA, row_ptr, col, dinv, b2, bufB);

    // Layer 3: bufB @ W3 (scaled) -> bufA ; aggregate+bias+log_softmax -> out
    gemm3_kernel<<<N_NODES / 16, 256, 0, stream>>>(bufB, W3, dinv, bufA);
    aggregate_kernel<16, false, true><<<(N_NODES * 16) / 256, 256, 0, stream>>>(
        bufA, row_ptr, col, dinv, b3, out);
}

// Round 12
// 537.316 us; speedup vs baseline: 1.6567x; 1.0319x over previous
//
#include <hip/hip_runtime.h>
#include <hip/hip_bf16.h>
#include <cstdint>
#include <cstddef>

#define N_NODES 100000
#define N_EDGES 1600000
#define F_IN 512
#define H1F 64
#define H2F 32
#define NCF 16
#define NB 782            // buckets of 128 nodes: ceil(100000/128)
#define NBLK 128          // edge chunks for counting sort
#define CHUNK 12500       // N_EDGES / NBLK exactly

typedef __attribute__((ext_vector_type(8))) short bf16x8;
typedef __attribute__((ext_vector_type(8))) unsigned short ushort8;
typedef __attribute__((ext_vector_type(4))) float f32x4;

__device__ inline short f2bf(float f) {
    // RNE f32 -> bf16 (inputs are finite, no NaN handling needed)
    uint32_t u = __builtin_bit_cast(uint32_t, f);
    return (short)((u + 0x7FFF + ((u >> 16) & 1)) >> 16);
}
__device__ inline float bf2f(unsigned short u) {
    uint32_t x = ((uint32_t)u) << 16;
    return __builtin_bit_cast(float, x);
}

// ---------------------------------------------------------------------------
// C1: per-chunk bucket histogram (LDS only) -> mat[blk][bucket]
// ---------------------------------------------------------------------------
__global__ __launch_bounds__(256) void count_kernel(const int* __restrict__ dst,
                                                    int* __restrict__ mat) {
    __shared__ int lh[NB];
    for (int i = threadIdx.x; i < NB; i += 256) lh[i] = 0;
    __syncthreads();
    int base = blockIdx.x * CHUNK;
    for (int j = base + threadIdx.x; j < base + CHUNK; j += 256)
        atomicAdd(&lh[dst[j] >> 7], 1);
    __syncthreads();
    for (int i = threadIdx.x; i < NB; i += 256)
        mat[blockIdx.x * NB + i] = lh[i];
}

// ---------------------------------------------------------------------------
// C2: per bucket, exclusive scan of the NBLK block-counts; bucket totals.
// ---------------------------------------------------------------------------
__global__ __launch_bounds__(NBLK) void colscan_kernel(int* __restrict__ mat,
                                                       int* __restrict__ total) {
    __shared__ int s[NBLK];
    int b = blockIdx.x;
    int t = threadIdx.x;
    int v = mat[t * NB + b];
    s[t] = v;
    __syncthreads();
    for (int o = 1; o < NBLK; o <<= 1) {
        int a = (t >= o) ? s[t - o] : 0;
        __syncthreads();
        s[t] += a;
        __syncthreads();
    }
    mat[t * NB + b] = s[t] - v;          // exclusive prefix across blocks
    if (t == NBLK - 1) total[b] = s[t];  // bucket total
}

// ---------------------------------------------------------------------------
// C3: exclusive scan of total[NB] -> boff[NB+1]; row_ptr[N]=E
// ---------------------------------------------------------------------------
__global__ __launch_bounds__(1024) void bscan_kernel(const int* __restrict__ total,
                                                     int* __restrict__ boff,
                                                     int* __restrict__ row_ptr) {
    __shared__ int s[1024];
    int t = threadIdx.x;
    int v = (t < NB) ? total[t] : 0;
    s[t] = v;
    __syncthreads();
    for (int o = 1; o < 1024; o <<= 1) {
        int a = (t >= o) ? s[t - o] : 0;
        __syncthreads();
        s[t] += a;
        __syncthreads();
    }
    if (t < NB) boff[t] = s[t] - v;
    if (t == 0) {
        boff[NB] = N_EDGES;
        row_ptr[N_NODES] = N_EDGES;
    }
}

// ---------------------------------------------------------------------------
// C4: placement pass — LDS cursors seeded from boff + mat (no global atomics).
// ---------------------------------------------------------------------------
__global__ __launch_bounds__(256) void place_kernel(const int* __restrict__ src,
                                                    const int* __restrict__ dst,
                                                    const int* __restrict__ boff,
                                                    const int* __restrict__ mat,
                                                    int* __restrict__ ebuf) {
    __shared__ int lcur[NB];
    for (int i = threadIdx.x; i < NB; i += 256)
        lcur[i] = boff[i] + mat[blockIdx.x * NB + i];
    __syncthreads();
    int base = blockIdx.x * CHUNK;
    for (int j = base + threadIdx.x; j < base + CHUNK; j += 256) {
        int d = dst[j];
        int b = d >> 7;
        int pos = atomicAdd(&lcur[b], 1);   // LDS atomic, ~16/bucket/block
        ebuf[pos] = src[j] | ((d & 127) << 17);
    }
}

// ---------------------------------------------------------------------------
// C5: per-bucket fine CSR build entirely in LDS.
// ---------------------------------------------------------------------------
__global__ __launch_bounds__(256) void bbuild_kernel(const int* __restrict__ ebuf,
                                                     const int* __restrict__ boff,
                                                     int* __restrict__ row_ptr,
                                                     int* __restrict__ col,
                                                     float* __restrict__ dinv) {
    __shared__ int lcnt[128], lexc[128];
    int b = blockIdx.x;
    int beg = boff[b], end = boff[b + 1];
    int t = threadIdx.x;
    if (t < 128) lcnt[t] = 0;
    __syncthreads();
    for (int j = beg + t; j < end; j += 256)
        atomicAdd(&lcnt[(ebuf[j] >> 17) & 127], 1);
    __syncthreads();
    if (t < 128) lexc[t] = lcnt[t];
    __syncthreads();
    for (int o = 1; o < 128; o <<= 1) {
        int a = (t < 128 && t >= o) ? lexc[t - o] : 0;
        __syncthreads();
        if (t < 128) lexc[t] += a;
        __syncthreads();
    }
    int node0 = b << 7;
    if (t < 128) {
        int n = node0 + t;
        if (n < N_NODES) {
            int ex = lexc[t] - lcnt[t];        // exclusive
            row_ptr[n] = beg + ex;
            dinv[n] = rsqrtf((float)(lcnt[t] + 1));
            lexc[t] = ex;                      // reuse as cursor
        }
    }
    __syncthreads();
    for (int j = beg + t; j < end; j += 256) {
        int v = ebuf[j];
        int li = (v >> 17) & 127;
        int p = atomicAdd(&lexc[li], 1);
        col[beg + p] = v & 0x1FFFF;
    }
}

// ---------------------------------------------------------------------------
// GEMM1 (bf16 MFMA): out[r][c] = bf16( dinv[r] * sum_k x[r][k]*W[k][c] )
// ---------------------------------------------------------------------------
__global__ __launch_bounds__(256) void gemm1_mfma(const float* __restrict__ x,
                                                  const float* __restrict__ W,
                                                  const float* __restrict__ dinv,
                                                  unsigned short* __restrict__ out) {
    __shared__ short As[2][4096];   // [kg]*1024 + (r ^ (kg<<2))*8 + i
    __shared__ short Bs[2][2048];   // byte: c*64 + ((kglocal*16) ^ ((c&3)<<4))
    const int tid = threadIdx.x;
    const int L = tid & 63;
    const int w = tid >> 6;          // wave 0..3
    const int brow = blockIdx.x * 128;

    f32x4 acc[2][4] = {};

    auto stageA = [&](int kt, int buf) {
        #pragma unroll
        for (int h = 0; h < 2; ++h) {
            int r  = (tid >> 2) + h * 64;   // 0..127
            int kg = tid & 3;               // k-group of 8
            int gr = brow + r;
            float4 v0 = make_float4(0.f, 0.f, 0.f, 0.f);
            float4 v1 = make_float4(0.f, 0.f, 0.f, 0.f);
            if (gr < N_NODES) {
                const float* p = &x[(size_t)gr * F_IN + kt * 32 + kg * 8];
                v0 = *reinterpret_cast<const float4*>(p);
                v1 = *reinterpret_cast<const float4*>(p + 4);
            }
            short t8[8] = {f2bf(v0.x), f2bf(v0.y), f2bf(v0.z), f2bf(v0.w),
                           f2bf(v1.x), f2bf(v1.y), f2bf(v1.z), f2bf(v1.w)};
            *reinterpret_cast<bf16x8*>(&As[buf][kg * 1024 + (r ^ (kg << 2)) * 8]) =
                *reinterpret_cast<bf16x8*>(t8);
        }
    };
    auto stageB = [&](int kt, int buf) {
        int k0 = kt * 32 + w * 8;
        short t8[8];
        #pragma unroll
        for (int i = 0; i < 8; ++i) t8[i] = f2bf(W[(size_t)(k0 + i) * H1F + L]);
        int byteoff = L * 64 + ((w * 16) ^ ((L & 3) << 4));
        *reinterpret_cast<bf16x8*>((char*)Bs[buf] + byteoff) =
            *reinterpret_cast<bf16x8*>(t8);
    };
    auto compute = [&](int buf) {
        const int kg = L >> 4;            // 0..3  (k = kg*8 + i)
        const int lr = L & 15;
        int r0 = w * 32 + lr;
        int r1 = r0 + 16;
        bf16x8 a0 = *reinterpret_cast<bf16x8*>(&As[buf][kg * 1024 + (r0 ^ (kg << 2)) * 8]);
        bf16x8 a1 = *reinterpret_cast<bf16x8*>(&As[buf][kg * 1024 + (r1 ^ (kg << 2)) * 8]);
        #pragma unroll
        for (int ni = 0; ni < 4; ++ni) {
            int c = ni * 16 + lr;
            bf16x8 b = *reinterpret_cast<bf16x8*>(
                (char*)Bs[buf] + c * 64 + ((kg * 16) ^ ((c & 3) << 4)));
            acc[0][ni] = __builtin_amdgcn_mfma_f32_16x16x32_bf16(a0, b, acc[0][ni], 0, 0, 0);
            acc[1][ni] = __builtin_amdgcn_mfma_f32_16x16x32_bf16(a1, b, acc[1][ni], 0, 0, 0);
        }
    };

    stageA(0, 0);
    stageB(0, 0);
    __syncthreads();
    for (int kt = 0; kt < 16; ++kt) {
        int cur = kt & 1;
        if (kt < 15) {
            stageA(kt + 1, cur ^ 1);
            stageB(kt + 1, cur ^ 1);
        }
        compute(cur);
        __syncthreads();
    }

    // epilogue: D mapping col=lane&15, row=(lane>>4)*4+i  [m89-verified]
    #pragma unroll
    for (int mi = 0; mi < 2; ++mi) {
        #pragma unroll
        for (int i = 0; i < 4; ++i) {
            int row = brow + w * 32 + mi * 16 + (L >> 4) * 4 + i;
            if (row < N_NODES) {
                float dv = dinv[row];
                #pragma unroll
                for (int ni = 0; ni < 4; ++ni)
                    out[(size_t)row * H1F + ni * 16 + (L & 15)] =
                        (unsigned short)f2bf(acc[mi][ni][i] * dv);
            }
        }
    }
}

// ---------------------------------------------------------------------------
// Fused layer-2: aggregate<64> (+b1,relu) then z@W2 scaled by dinv -> bf16 h2'
// Block = 4 nodes x 64 features (wave per node). z never touches HBM.
// ---------------------------------------------------------------------------
__global__ __launch_bounds__(256) void agg64_gemm2(const unsigned short* __restrict__ h,
                                                   const int* __restrict__ row_ptr,
                                                   const int* __restrict__ col,
                                                   const float* __restrict__ dinv,
                                                   const float* __restrict__ b1,
                                                   const float* __restrict__ W2,
                                                   unsigned short* __restrict__ out) {
    __shared__ float zs[4][64];
    __shared__ float ws[64][32];   // W2, 8 KB
    int tid = threadIdx.x;
    #pragma unroll
    for (int i = 0; i < 2; ++i) {
        int f4 = tid + i * 256;    // 512 float4
        reinterpret_cast<float4*>(&ws[0][0])[f4] = reinterpret_cast<const float4*>(W2)[f4];
    }
    int n = blockIdx.x * 4 + (tid >> 6);
    int f = tid & 63;
    int beg = row_ptr[n];
    int end = row_ptr[n + 1];
    float sum = bf2f(h[(size_t)n * 64 + f]);   // self-loop
    int j = beg;
    for (; j + 3 < end; j += 4) {
        int c0 = col[j], c1 = col[j + 1], c2 = col[j + 2], c3 = col[j + 3];
        float s0 = bf2f(h[(size_t)c0 * 64 + f]);
        float s1 = bf2f(h[(size_t)c1 * 64 + f]);
        float s2 = bf2f(h[(size_t)c2 * 64 + f]);
        float s3 = bf2f(h[(size_t)c3 * 64 + f]);
        sum += (s0 + s1) + (s2 + s3);
    }
    for (; j < end; ++j) sum += bf2f(h[(size_t)col[j] * 64 + f]);
    float val = fmaxf(sum * dinv[n] + b1[f], 0.f);
    zs[tid >> 6][f] = val;
    __syncthreads();
    if (tid < 128) {
        int ln = tid >> 5;     // 0..3
        int c = tid & 31;
        float acc = 0.f;
        #pragma unroll
        for (int k = 0; k < 64; ++k) acc += zs[ln][k] * ws[k][c];
        int gn = blockIdx.x * 4 + ln;
        out[(size_t)gn * H2F + c] = (unsigned short)f2bf(acc * dinv[gn]);
    }
}

// ---------------------------------------------------------------------------
// Fused layer-3: aggregate<32> (+b2,relu) then z@W3 scaled by dinv -> bf16 h3'
// Block = 8 nodes x 32 features.
// ---------------------------------------------------------------------------
__global__ __launch_bounds__(256) void agg32_gemm3(const unsigned short* __restrict__ h,
                                                   const int* __restrict__ row_ptr,
                                                   const int* __restrict__ col,
                                                   const float* __restrict__ dinv,
                                                   const float* __restrict__ b2,
                                                   const float* __restrict__ W3,
                                                   unsigned short* __restrict__ out) {
    __shared__ float zs[8][32];
    __shared__ float ws[32][16];   // W3, 2 KB
    int tid = threadIdx.x;
    if (tid < 128)
        reinterpret_cast<float4*>(&ws[0][0])[tid] = reinterpret_cast<const float4*>(W3)[tid];
    int n = blockIdx.x * 8 + (tid >> 5);
    int f = tid & 31;
    int beg = row_ptr[n];
    int end = row_ptr[n + 1];
    float sum = bf2f(h[(size_t)n * 32 + f]);   // self-loop
    int j = beg;
    for (; j + 3 < end; j += 4) {
        int c0 = col[j], c1 = col[j + 1], c2 = col[j + 2], c3 = col[j + 3];
        float s0 = bf2f(h[(size_t)c0 * 32 + f]);
        float s1 = bf2f(h[(size_t)c1 * 32 + f]);
        float s2 = bf2f(h[(size_t)c2 * 32 + f]);
        float s3 = bf2f(h[(size_t)c3 * 32 + f]);
        sum += (s0 + s1) + (s2 + s3);
    }
    for (; j < end; ++j) sum += bf2f(h[(size_t)col[j] * 32 + f]);
    float val = fmaxf(sum * dinv[n] + b2[f], 0.f);
    zs[tid >> 5][f] = val;
    __syncthreads();
    if (tid < 128) {
        int ln = tid >> 4;     // 0..7
        int c = tid & 15;
        float acc = 0.f;
        #pragma unroll
        for (int k = 0; k < 32; ++k) acc += zs[ln][k] * ws[k][c];
        int gn = blockIdx.x * 8 + ln;
        out[(size_t)gn * NCF + c] = (unsigned short)f2bf(acc * dinv[gn]);
    }
}

// ---------------------------------------------------------------------------
// Final: aggregate<16> + bias + log_softmax -> f32 out
// ---------------------------------------------------------------------------
__global__ __launch_bounds__(256) void agg16_lsm(const unsigned short* __restrict__ h,
                                                 const int* __restrict__ row_ptr,
                                                 const int* __restrict__ col,
                                                 const float* __restrict__ dinv,
                                                 const float* __restrict__ b3,
                                                 float* __restrict__ out) {
    int tid = blockIdx.x * 256 + threadIdx.x;
    int n = tid / NCF;
    int f = tid % NCF;
    int beg = row_ptr[n];
    int end = row_ptr[n + 1];
    float sum = bf2f(h[(size_t)n * NCF + f]);
    int j = beg;
    for (; j + 3 < end; j += 4) {
        int c0 = col[j], c1 = col[j + 1], c2 = col[j + 2], c3 = col[j + 3];
        float s0 = bf2f(h[(size_t)c0 * NCF + f]);
        float s1 = bf2f(h[(size_t)c1 * NCF + f]);
        float s2 = bf2f(h[(size_t)c2 * NCF + f]);
        float s3 = bf2f(h[(size_t)c3 * NCF + f]);
        sum += (s0 + s1) + (s2 + s3);
    }
    for (; j < end; ++j) sum += bf2f(h[(size_t)col[j] * NCF + f]);
    float val = sum * dinv[n] + b3[f];
    float m = val;
    #pragma unroll
    for (int o = 1; o < NCF; o <<= 1) m = fmaxf(m, __shfl_xor(m, o));
    float ex = expf(val - m);
    float s = ex;
    #pragma unroll
    for (int o = 1; o < NCF; o <<= 1) s += __shfl_xor(s, o);
    out[(size_t)n * NCF + f] = val - m - logf(s);
}

// ---------------------------------------------------------------------------
extern "C" void kernel_launch(void* const* d_in, const int* in_sizes, int n_in,
                              void* d_out, int out_size, void* d_ws, size_t ws_size,
                              hipStream_t stream) {
    const float* x  = (const float*)d_in[0];
    const int*   ei = (const int*)d_in[1];
    const float* W1 = (const float*)d_in[2];
    const float* b1 = (const float*)d_in[3];
    const float* W2 = (const float*)d_in[4];
    const float* b2 = (const float*)d_in[5];
    const float* W3 = (const float*)d_in[6];
    const float* b3 = (const float*)d_in[7];
    float* out = (float*)d_out;

    const int* src = ei;              // edge_index[0]
    const int* dst = ei + N_EDGES;    // edge_index[1]

    char* ws = (char*)d_ws;
    size_t off = 0;
    auto alloc = [&](size_t bytes) -> void* {
        void* p = ws + off;
        off += (bytes + 255) & ~(size_t)255;
        return p;
    };
    int*            row_ptr = (int*)alloc((size_t)(N_NODES + 1) * 4);
    float*          dinv    = (float*)alloc((size_t)N_NODES * 4);
    int*            col     = (int*)alloc((size_t)N_EDGES * 4);
    unsigned short* bufA    = (unsigned short*)alloc((size_t)N_NODES * 64 * 2);  // h1'
    unsigned short* bufB    = (unsigned short*)alloc((size_t)N_NODES * 32 * 2);  // h2'
    unsigned short* bufC    = (unsigned short*)alloc((size_t)N_NODES * 16 * 2);  // h3'
    int*            mat     = (int*)alloc((size_t)NBLK * NB * 4);
    int*            total   = (int*)alloc((size_t)NB * 4);
    int*            boff    = (int*)alloc((size_t)(NB + 1) * 4);
    int*            ebuf    = (int*)bufA;  // alias: 6.4MB < 12.8MB, build precedes gemm1

    count_kernel<<<NBLK, 256, 0, stream>>>(dst, mat);
    colscan_kernel<<<NB, NBLK, 0, stream>>>(mat, total);
    bscan_kernel<<<1, 1024, 0, stream>>>(total, boff, row_ptr);
    place_kernel<<<NBLK, 256, 0, stream>>>(src, dst, boff, mat, ebuf);
    bbuild_kernel<<<NB, 256, 0, stream>>>(ebuf, boff, row_ptr, col, dinv);

    // Layer 1: x @ W1 (scaled, bf16 MFMA) -> bufA (h1')
    gemm1_mfma<<<(N_NODES + 127) / 128, 256, 0, stream>>>(x, W1, dinv, bufA);
    // Fused: aggregate<64>+relu+@W2*dinv -> bufB (h2')
    agg64_gemm2<<<N_NODES / 4, 256, 0, stream>>>(bufA, row_ptr, col, dinv, b1, W2, bufB);
    // Fused: aggregate<32>+relu+@W3*dinv -> bufC (h3')
    agg32_gemm3<<<N_NODES / 8, 256, 0, stream>>>(bufB, row_ptr, col, dinv, b2, W3, bufC);
    // Final: aggregate<16>+bias+log_softmax -> out (f32)
    agg16_lsm<<<(N_NODES * NCF) / 256, 256, 0, stream>>>(bufC, row_ptr, col, dinv, b3, out);
}